// Round 8
// baseline (125.274 us; speedup 1.0000x reference)
//
#include <hip/hip_runtime.h>

// ---------------------------------------------------------------------------
// GraphAttn: out = relu( (mergeheads( tanh((QK^T/4) * adj) @ V )) @ wo )
// B=32, N=512, F_IN=64, H=8, D=16, OUT=128.
// v5: attn m-loop -> 4-buffer rotation, 3-tiles-ahead prefetch (static names,
//     fully unrolled), s_setprio(1) around compute cluster. Staging, fused
//     oproj tail, prep, qkv identical to v4.
// ---------------------------------------------------------------------------

typedef __bf16 bf16x8 __attribute__((ext_vector_type(8)));
typedef __bf16 bf16x4 __attribute__((ext_vector_type(4)));
typedef float  f32x4  __attribute__((ext_vector_type(4)));

#define MFMA16(a, b, c) __builtin_amdgcn_mfma_f32_16x16x32_bf16((a), (b), (c), 0, 0, 0)

// ---------------------------------------------------------------------------
// prep: WTb[j][k] = w{q,k,v}[k][j&127] (384x64), WoTb[j][k] = wo[k][j] (128x128)
// ---------------------------------------------------------------------------
__global__ __launch_bounds__(256) void prep_kernel(
    const float* __restrict__ wq, const float* __restrict__ wk,
    const float* __restrict__ wv, const float* __restrict__ wo,
    __bf16* __restrict__ WTb, __bf16* __restrict__ WoTb)
{
    int idx = blockIdx.x * 256 + threadIdx.x;
    if (idx < 6144) {                       // 96 j-groups x 64 k
        int j4 = idx % 96, k = idx / 96, j = j4 * 4;
        const float* w = (j < 128) ? wq : ((j < 256) ? wk : wv);
        f32x4 v = *(const f32x4*)&w[k * 128 + (j & 127)];
#pragma unroll
        for (int e = 0; e < 4; ++e) WTb[(j + e) * 64 + k] = (__bf16)v[e];
    } else if (idx < 6144 + 4096) {         // 32 j-groups x 128 k
        int i2 = idx - 6144;
        int j4 = i2 % 32, k = i2 / 32, j = j4 * 4;
        f32x4 v = *(const f32x4*)&wo[k * 128 + j];
#pragma unroll
        for (int e = 0; e < 4; ++e) WoTb[(j + e) * 128 + k] = (__bf16)v[e];
    }
}

// ---------------------------------------------------------------------------
// qkv: Q,K = [bh][n][16] row-major bf16; VT = [bh][16][n].
// ---------------------------------------------------------------------------
__global__ __launch_bounds__(256) void qkv_kernel(
    const float* __restrict__ x, const __bf16* __restrict__ WTb,
    __bf16* __restrict__ Qb, __bf16* __restrict__ Kb, __bf16* __restrict__ VT)
{
    const int tid = threadIdx.x, lane = tid & 63, w = tid >> 6;
    const int g = lane >> 4, lr = lane & 15;
    const long R0 = (long)blockIdx.x * 16;
    const int b = (int)(R0 >> 9);
    const int nloc = (int)(R0 & 511) + g * 4;

    bf16x8 af[2];
#pragma unroll
    for (int kk = 0; kk < 2; ++kk) {
        const float* xp = x + (R0 + lr) * 64 + kk * 32 + g * 8;
        f32x4 x0 = *(const f32x4*)xp, x1 = *(const f32x4*)(xp + 4);
        bf16x8 a;
#pragma unroll
        for (int e = 0; e < 4; ++e) { a[e] = (__bf16)x0[e]; a[4 + e] = (__bf16)x1[e]; }
        af[kk] = a;
    }

#pragma unroll 2
    for (int i = 0; i < 6; ++i) {
        const int j0 = (w * 6 + i) * 16;
        f32x4 acc = {0.f, 0.f, 0.f, 0.f};
#pragma unroll
        for (int kk = 0; kk < 2; ++kk) {
            bf16x8 bf = *(const bf16x8*)&WTb[(j0 + lr) * 64 + kk * 32 + g * 8];
            acc = MFMA16(af[kk], bf, acc);
        }
        const int jj = (j0 + lr) & 127, hh = jj >> 4, d = jj & 15;
        const int bh = b * 8 + hh, t = j0 >> 7;
        if (t == 2) {
            bf16x4 pk;
#pragma unroll
            for (int r = 0; r < 4; ++r) pk[r] = (__bf16)acc[r];
            *(bf16x4*)&VT[((long)bh * 16 + d) * 512 + nloc] = pk;
        } else {
            __bf16* dst = t ? Kb : Qb;
#pragma unroll
            for (int r = 0; r < 4; ++r)
                dst[((long)bh * 512 + nloc + r) * 16 + d] = (__bf16)acc[r];
        }
    }
}

// ---------------------------------------------------------------------------
// attn+oproj fused.  Block = (b, 32-row n-strip), 8 waves = 8 heads.
// XCD-bijective swizzle; adjL bf16[32][520] pre-scaled; m-loop = 4-buffer
// rotation with 3-tiles-ahead prefetch; fused oproj tail via LDS h-tile.
// ---------------------------------------------------------------------------
__device__ __forceinline__ float tanh_e(float x) {
    // x = s * (adj*C), C = 0.25*2*log2(e);  tanh(s*adj/4) = 1 - 2/(2^x + 1)
    float e = __builtin_amdgcn_exp2f(x);
    return 1.0f - 2.0f * __builtin_amdgcn_rcpf(e + 1.0f);
}

struct Tile {
    bf16x8 kf0, kf1;
    bf16x4 v0, v1;
};

__device__ __forceinline__ Tile load_tile(
    int m0, bool ga, const __bf16* Kbase, int lr, int g, const __bf16* Vrow)
{
    Tile t;
    t.kf0 = {}; t.kf1 = {};
    if (ga) {
        t.kf0 = *(const bf16x8*)&Kbase[(m0 + lr) * 16 + g * 8];
        t.kf1 = *(const bf16x8*)&Kbase[(m0 + 16 + lr) * 16 + g * 8];
    }
    t.v0 = *(const bf16x4*)&Vrow[m0 + g * 4];
    t.v1 = *(const bf16x4*)&Vrow[m0 + 16 + g * 4];
    return t;
}

__device__ __forceinline__ void compute_tile(
    const Tile& t, int m0, bf16x8 qf0, bf16x8 qf1,
    const __bf16* aR0, const __bf16* aR1, int g,
    f32x4& acc0, f32x4& acc1)
{
    // adj (bf16, pre-scaled) from LDS; issue before MFMAs so latency overlaps
    bf16x4 ba00 = *(const bf16x4*)&aR0[m0 + g * 4];
    bf16x4 ba01 = *(const bf16x4*)&aR0[m0 + 16 + g * 4];
    bf16x4 ba10 = *(const bf16x4*)&aR1[m0 + g * 4];
    bf16x4 ba11 = *(const bf16x4*)&aR1[m0 + 16 + g * 4];

    __builtin_amdgcn_s_setprio(1);
    const f32x4 z = {0.f, 0.f, 0.f, 0.f};
    // lane(g,lr): s[r] = S[m = m0(+16) + g*4 + r][n-sub row lr]
    f32x4 s00 = MFMA16(t.kf0, qf0, z);
    f32x4 s01 = MFMA16(t.kf1, qf0, z);
    f32x4 s10 = MFMA16(t.kf0, qf1, z);
    f32x4 s11 = MFMA16(t.kf1, qf1, z);

    bf16x8 p0, p1, vf;
#pragma unroll
    for (int r = 0; r < 4; ++r) {
        p0[r]     = (__bf16)tanh_e(s00[r] * (float)ba00[r]);
        p0[4 + r] = (__bf16)tanh_e(s01[r] * (float)ba01[r]);
        p1[r]     = (__bf16)tanh_e(s10[r] * (float)ba10[r]);
        p1[4 + r] = (__bf16)tanh_e(s11[r] * (float)ba11[r]);
        vf[r]     = t.v0[r];
        vf[4 + r] = t.v1[r];
    }
    acc0 = MFMA16(p0, vf, acc0);   // h[n-sub0 = n0+g*4+r][d=lr]
    acc1 = MFMA16(p1, vf, acc1);   // h[n-sub1 = n0+16+g*4+r][d=lr]
    __builtin_amdgcn_s_setprio(0);
}

__global__ __launch_bounds__(512, 4) void attn_kernel(
    const float* __restrict__ adj,
    const __bf16* __restrict__ Qb, const __bf16* __restrict__ Kb,
    const __bf16* __restrict__ VT, const __bf16* __restrict__ WoTb,
    float* __restrict__ out)
{
    __shared__ __align__(16) char smem[33280];   // adjL bf16[32][520] | hL f32[32][132]

    const int tid  = threadIdx.x;
    const int lane = tid & 63;
    const int h    = tid >> 6;        // wave = head
    const int g    = lane >> 4;
    const int lr   = lane & 15;

    // XCD-bijective decode: l = ((b>>3)*16 + strip)*8 + (b&7)
    const int l  = blockIdx.x;
    const int q  = l >> 3;
    const int b  = (q >> 4) * 8 + (l & 7);
    const int n0 = (q & 15) * 32;
    const int bh = b * 8 + h;

    // ---- stage adj strip (32x512 f32 -> bf16*C), nontemporal, padded rows --
    const float C = 0.7213475204444817f;   // 0.25 * 2 * log2(e)
    __bf16* adjL = (__bf16*)smem;
    const float* strip = adj + ((long)b * 512 + n0) * 512;
#pragma unroll
    for (int i = 0; i < 8; ++i) {
        int o = i * 2048 + tid * 4;          // f32 index, row-major 512
        f32x4 v = __builtin_nontemporal_load((const f32x4*)(strip + o));
        int row = o >> 9, col = o & 511;
        bf16x4 w;
#pragma unroll
        for (int e = 0; e < 4; ++e) w[e] = (__bf16)(v[e] * C);
        *(bf16x4*)&adjL[row * 520 + col] = w;
    }

    const bool ga = (g < 2);
    bf16x8 qf0 = {}, qf1 = {};   // B-operand: Q[n][d], zeros for k>=16
    if (ga) {
        qf0 = *(const bf16x8*)&Qb[((long)bh * 512 + n0 + lr) * 16 + g * 8];
        qf1 = *(const bf16x8*)&Qb[((long)bh * 512 + n0 + 16 + lr) * 16 + g * 8];
    }
    const __bf16* Kbase = Kb + (long)bh * 512 * 16;
    const __bf16* Vrow  = VT + ((long)bh * 16 + lr) * 512;   // row d = lr
    const __bf16* aR0   = adjL + lr * 520;                   // n = n0+lr
    const __bf16* aR1   = adjL + (16 + lr) * 520;            // n = n0+16+lr

    __syncthreads();

    f32x4 acc0 = {0.f, 0.f, 0.f, 0.f}, acc1 = {0.f, 0.f, 0.f, 0.f};

    // ---- m-loop: 4-buffer rotation, loads issued 3 tiles ahead -------------
    Tile T0 = load_tile(0 * 32, ga, Kbase, lr, g, Vrow);
    Tile T1 = load_tile(1 * 32, ga, Kbase, lr, g, Vrow);
    Tile T2 = load_tile(2 * 32, ga, Kbase, lr, g, Vrow);
    Tile T3;
#pragma unroll
    for (int j = 0; j < 3; ++j) {
        const int t = j * 4;
        T3 = load_tile((t + 3) * 32, ga, Kbase, lr, g, Vrow);
        compute_tile(T0, t * 32,       qf0, qf1, aR0, aR1, g, acc0, acc1);
        T0 = load_tile((t + 4) * 32, ga, Kbase, lr, g, Vrow);
        compute_tile(T1, (t + 1) * 32, qf0, qf1, aR0, aR1, g, acc0, acc1);
        T1 = load_tile((t + 5) * 32, ga, Kbase, lr, g, Vrow);
        compute_tile(T2, (t + 2) * 32, qf0, qf1, aR0, aR1, g, acc0, acc1);
        T2 = load_tile((t + 6) * 32, ga, Kbase, lr, g, Vrow);
        compute_tile(T3, (t + 3) * 32, qf0, qf1, aR0, aR1, g, acc0, acc1);
    }
    // epilogue: t = 12..15 (T0=12, T1=13, T2=14)
    T3 = load_tile(15 * 32, ga, Kbase, lr, g, Vrow);
    compute_tile(T0, 12 * 32, qf0, qf1, aR0, aR1, g, acc0, acc1);
    compute_tile(T1, 13 * 32, qf0, qf1, aR0, aR1, g, acc0, acc1);
    compute_tile(T2, 14 * 32, qf0, qf1, aR0, aR1, g, acc0, acc1);
    compute_tile(T3, 15 * 32, qf0, qf1, aR0, aR1, g, acc0, acc1);

    // ---- fused oproj: h -> LDS (reuse adj buffer) -> MFMA with wo -> relu --
    __syncthreads();                       // all waves done reading adjL
    float* hL = (float*)smem;              // [32][132] f32
#pragma unroll
    for (int r = 0; r < 4; ++r) {
        hL[(g * 4 + r) * 132 + h * 16 + lr]        = acc0[r];
        hL[(16 + g * 4 + r) * 132 + h * 16 + lr]   = acc1[r];
    }
    __syncthreads();

    // A-frags: h[t*16+lr][kt*32+g*8..+8); B-frags: wo^T[j=h*16+lr][same k]
    f32x4 o0 = {0.f, 0.f, 0.f, 0.f}, o1 = {0.f, 0.f, 0.f, 0.f};
#pragma unroll
    for (int kt = 0; kt < 4; ++kt) {
        bf16x8 wf = *(const bf16x8*)&WoTb[(h * 16 + lr) * 128 + kt * 32 + g * 8];
        const float* hp0 = &hL[lr * 132 + kt * 32 + g * 8];
        const float* hp1 = &hL[(16 + lr) * 132 + kt * 32 + g * 8];
        f32x4 ha = *(const f32x4*)hp0, hb = *(const f32x4*)(hp0 + 4);
        f32x4 hc = *(const f32x4*)hp1, hd = *(const f32x4*)(hp1 + 4);
        bf16x8 a0, a1;
#pragma unroll
        for (int e = 0; e < 4; ++e) {
            a0[e] = (__bf16)ha[e]; a0[4 + e] = (__bf16)hb[e];
            a1[e] = (__bf16)hc[e]; a1[4 + e] = (__bf16)hd[e];
        }
        o0 = MFMA16(a0, wf, o0);
        o1 = MFMA16(a1, wf, o1);
    }

    const long obase = (long)b * 512 + n0;
#pragma unroll
    for (int r = 0; r < 4; ++r) {
        out[(obase + g * 4 + r) * 128 + h * 16 + lr]      = fmaxf(o0[r], 0.f);
        out[(obase + 16 + g * 4 + r) * 128 + h * 16 + lr] = fmaxf(o1[r], 0.f);
    }
}

// ---------------------------------------------------------------------------
extern "C" void kernel_launch(void* const* d_in, const int* in_sizes, int n_in,
                              void* d_out, int out_size, void* d_ws, size_t ws_size,
                              hipStream_t stream) {
    const float* x   = (const float*)d_in[0];
    const float* adj = (const float*)d_in[1];
    const float* wq  = (const float*)d_in[2];
    const float* wk  = (const float*)d_in[3];
    const float* wv  = (const float*)d_in[4];
    const float* wo  = (const float*)d_in[5];
    float* out = (float*)d_out;

    char* wsb = (char*)d_ws;
    __bf16* WTb  = (__bf16*)wsb;                    // 384*64  bf16 = 48 KiB
    __bf16* WoTb = (__bf16*)(wsb + 49152);          // 128*128 bf16 = 32 KiB
    __bf16* Qb   = (__bf16*)(wsb + 81920);          // 256*512*16 bf16 = 4 MiB
    __bf16* Kb   = Qb + 2097152;
    __bf16* VT   = Kb + 2097152;                    // [bh][16][512]

    prep_kernel<<<40, 256, 0, stream>>>(wq, wk, wv, wo, WTb, WoTb);
    qkv_kernel<<<1024, 256, 0, stream>>>(x, WTb, Qb, Kb, VT);
    attn_kernel<<<512, 512, 0, stream>>>(adj, Qb, Kb, VT, WoTb, out);
}